// Round 3
// baseline (181.523 us; speedup 1.0000x reference)
//
#include <hip/hip_runtime.h>
#include <stdint.h>

constexpr int Bq = 8, Nq = 2048, Mq = 2048, Dq = 256;
constexpr int TILE = 128;          // 128x128 output tile per block
constexpr int KC = 32;             // fp32 k per chunk == MFMA K
constexpr int NCH = Dq / KC;       // 8 chunks
constexpr int LDS_S = 40;          // fallback kernel: 80B row stride

typedef float f32x4 __attribute__((ext_vector_type(4)));
typedef _Float16 f16x8 __attribute__((ext_vector_type(8)));
typedef _Float16 f16x4 __attribute__((ext_vector_type(4)));
typedef __fp16 fp16x2 __attribute__((ext_vector_type(2)));  // cvt_pkrtz native type

__device__ __forceinline__ uint32_t f2sortable(float f) {
  uint32_t u = __float_as_uint(f);
  return (u & 0x80000000u) ? ~u : (u | 0x80000000u);
}
__device__ __forceinline__ float sortable2f(uint32_t s) {
  uint32_t u = (s & 0x80000000u) ? (s ^ 0x80000000u) : ~s;
  return __uint_as_float(u);
}

__device__ __forceinline__ void load16(float* d, const float* __restrict__ p) {
  *(float4*)&d[0]  = *(const float4*)(p + 0);
  *(float4*)&d[4]  = *(const float4*)(p + 4);
  *(float4*)&d[8]  = *(const float4*)(p + 8);
  *(float4*)&d[12] = *(const float4*)(p + 12);
}

// Truncation split: h = x with low 13 mantissa bits cleared (exactly f16-
// representable; residual x-h exact by Sterbenz). al kept UNSCALED so all
// three MFMA terms share one accumulator: a.b ~= ah.bh + ah.bl + al.bh.
// Dropped al.bl ~ 2^-21|a||b| -> sim error ~1e-8; f16-denorm loss on tiny
// al -> sim error < 5e-7. Both negligible vs mean argmax gap 0.013.
__device__ __forceinline__ void split8(const float* x, f16x8* hi, f16x8* lo,
                                       float& sq) {
  union { f16x8 v; fp16x2 p[4]; } H, L;
#pragma unroll
  for (int j = 0; j < 4; ++j) {
    float x0 = x[2 * j], x1 = x[2 * j + 1];
    sq = fmaf(x0, x0, sq);
    sq = fmaf(x1, x1, sq);
    float h0 = __uint_as_float(__float_as_uint(x0) & 0xFFFFE000u);
    float h1 = __uint_as_float(__float_as_uint(x1) & 0xFFFFE000u);
    H.p[j] = __builtin_amdgcn_cvt_pkrtz(h0, h1);          // exact (13-bit mantissa)
    L.p[j] = __builtin_amdgcn_cvt_pkrtz(x0 - h0, x1 - h1); // RTZ on residual: fine
  }
  *hi = H.v;
  *lo = L.v;
}

// ---------------------------------------------------------------------------
// Preprocess fp32 -> chunked f16 hi/lo + inv-norms. Layout X[b][chunk][row][32]
// f16 (64 B rows): a wave's MFMA fragment read (16 rows x 64 B) is a fully
// coalesced, contiguous 1 KB global read, and the 4 row-tiles of a 64-row
// wave strip sit at +1024 B steps -> imm-offset loads from ONE address.
// ---------------------------------------------------------------------------

__global__ __launch_bounds__(256)
void prep_kernel(const float* __restrict__ src, const float* __restrict__ dst,
                 _Float16* __restrict__ Ah, _Float16* __restrict__ Al,
                 _Float16* __restrict__ Bh, _Float16* __restrict__ Bl,
                 float* __restrict__ invnx, float* __restrict__ invny) {
  const int lane = threadIdx.x & 63;
  const int wv = threadIdx.x >> 6;
  const int r = blockIdx.x * 4 + wv;  // global row 0..16383 (one wave per row)

  const float* x;
  _Float16 *h, *l;
  float* inv;
  if (blockIdx.y == 0) { x = src; h = Ah; l = Al; inv = invnx; }
  else                 { x = dst; h = Bh; l = Bl; inv = invny; }

  // lane covers 4 consecutive k: coalesced 1 KB/wave read
  float4 v = *(const float4*)(x + (size_t)r * Dq + lane * 4);
  float sq = 0.f;
  union { f16x4 v; fp16x2 p[2]; } H, L;
  float e[4] = {v.x, v.y, v.z, v.w};
#pragma unroll
  for (int j = 0; j < 2; ++j) {
    float x0 = e[2 * j], x1 = e[2 * j + 1];
    sq = fmaf(x0, x0, sq);
    sq = fmaf(x1, x1, sq);
    float h0 = __uint_as_float(__float_as_uint(x0) & 0xFFFFE000u);
    float h1 = __uint_as_float(__float_as_uint(x1) & 0xFFFFE000u);
    H.p[j] = __builtin_amdgcn_cvt_pkrtz(h0, h1);
    L.p[j] = __builtin_amdgcn_cvt_pkrtz(x0 - h0, x1 - h1);
  }
#pragma unroll
  for (int m = 1; m <= 32; m <<= 1) sq += __shfl_xor(sq, m);

  const int b = r >> 11, row = r & 2047;
  const int c = lane >> 3, ko = (lane & 7) * 4;  // chunk, k-within-chunk
  size_t idx = ((size_t)(b * NCH + c) * 2048 + row) * KC + ko;
  *(f16x4*)&h[idx] = H.v;
  *(f16x4*)&l[idx] = L.v;
  if (lane == 0) inv[r] = 1.0f / sqrtf(sq);  // norms ~16; eps clamp never active
}

// ---------------------------------------------------------------------------
// Main kernel: NO LDS, NO barriers. Register double-buffer at chunk
// granularity, with sched_barrier(0) fences PINNING the schedule:
//   [issue 16 loads of set k+1] | fence | [48 MFMAs of set k] | fence | ...
// Round-2 failure mode (VGPR_Count=64): without fences the compiler sank the
// prefetch loads to just-before-use to save registers, exposing L2 latency
// 8x per chunk (MfmaUtil 21%). Pinning keeps both FragSets live (~214 unified
// regs -> 2 waves/SIMD) and turns the auto-inserted s_waitcnt into a counted
// non-draining wait (T4): s1's 16 loads ride out over ~768 cyc of s0 MFMAs.
// ---------------------------------------------------------------------------

constexpr size_t CSTR = (size_t)2048 * KC;  // chunk stride (elements)

struct FragSet { f16x8 ah[4], al[4], bh[4], bl[4]; };

__device__ __forceinline__ void load_set(const _Float16* __restrict__ pah,
                                         const _Float16* __restrict__ pal,
                                         const _Float16* __restrict__ pbh,
                                         const _Float16* __restrict__ pbl,
                                         FragSet& s) {
  // 4 addresses, 4 imm-offset (0/1024/2048/3072 B) loads each: row-tile t is
  // t*16 rows * 64 B = t*1024 B from the per-lane base (compiler folds).
#pragma unroll
  for (int t = 0; t < 4; ++t) {
    s.ah[t] = *(const f16x8*)(pah + t * 16 * KC);
    s.al[t] = *(const f16x8*)(pal + t * 16 * KC);
    s.bh[t] = *(const f16x8*)(pbh + t * 16 * KC);
    s.bl[t] = *(const f16x8*)(pbl + t * 16 * KC);
  }
}

__device__ __forceinline__ void mfma_set(const FragSet& s, f32x4 acc[4][4]) {
#pragma unroll
  for (int rt = 0; rt < 4; ++rt)
#pragma unroll
    for (int ct = 0; ct < 4; ++ct) {
      acc[rt][ct] = __builtin_amdgcn_mfma_f32_16x16x32_f16(s.ah[rt], s.bh[ct], acc[rt][ct], 0, 0, 0);
      acc[rt][ct] = __builtin_amdgcn_mfma_f32_16x16x32_f16(s.ah[rt], s.bl[ct], acc[rt][ct], 0, 0, 0);
      acc[rt][ct] = __builtin_amdgcn_mfma_f32_16x16x32_f16(s.al[rt], s.bh[ct], acc[rt][ct], 0, 0, 0);
    }
}

__global__ __launch_bounds__(256, 2)
void simmax_reg(const _Float16* __restrict__ Ah, const _Float16* __restrict__ Al,
                const _Float16* __restrict__ Bh, const _Float16* __restrict__ Bl,
                const float* __restrict__ invnx, const float* __restrict__ invny,
                unsigned long long* __restrict__ best) {
  // T1 XCD swizzle (bijective: 2048 % 8 == 0). XCD k owns the 256 tiles of
  // b=k: per-XCD working set = A(b)+B(b) = 4 MB = one L2. Validated round 2:
  // FETCH_SIZE 74 -> 16.6 MB.
  const int orig = blockIdx.x;
  const int logical = (orig & 7) * 256 + (orig >> 3);
  const int b = logical >> 8;
  const int nt = (logical >> 4) & 15;
  const int mt = logical & 15;

  const int tid = threadIdx.x;
  const int lane = tid & 63;
  const int wave = tid >> 6;
  const int wy = wave >> 1, wx = wave & 1;  // wave tile: rows wy*64, cols wx*64
  const int ln15 = lane & 15, lq = lane >> 4;

  // per-lane fragment base: arr[(b*NCH+0)*2048 + row0 + ln15][lq*8]
  const size_t rbA = ((size_t)(b * NCH) * 2048 + nt * TILE + wy * 64 + ln15) * KC + lq * 8;
  const size_t rbB = ((size_t)(b * NCH) * 2048 + mt * TILE + wx * 64 + ln15) * KC + lq * 8;
  const _Float16* Abh = Ah + rbA;
  const _Float16* Abl = Al + rbA;
  const _Float16* Bbh = Bh + rbB;
  const _Float16* Bbl = Bl + rbB;

  f32x4 acc[4][4];
#pragma unroll
  for (int i = 0; i < 4; ++i)
#pragma unroll
    for (int j = 0; j < 4; ++j) acc[i][j] = (f32x4){0.f, 0.f, 0.f, 0.f};

  FragSet s0, s1;  // static ping-pong (rule #20: all indices compile-time)
  load_set(Abh, Abl, Bbh, Bbl, s0);
#pragma unroll
  for (int cc = 0; cc < NCH; cc += 2) {
    {
      const size_t o = (size_t)(cc + 1) * CSTR;
      load_set(Abh + o, Abl + o, Bbh + o, Bbl + o, s1);  // issue odd chunk
    }
    __builtin_amdgcn_sched_barrier(0);  // pin: s1 loads issue BEFORE s0 MFMAs
    mfma_set(s0, acc);                  // covers s1's L2 latency (~768 cyc)
    __builtin_amdgcn_sched_barrier(0);
    if (cc + 2 < NCH) {
      const size_t o = (size_t)(cc + 2) * CSTR;
      load_set(Abh + o, Abl + o, Bbh + o, Bbl + o, s0);  // issue next even
    }
    __builtin_amdgcn_sched_barrier(0);
    mfma_set(s1, acc);                  // covers s0's L2 latency
    __builtin_amdgcn_sched_barrier(0);
  }

  // epilogue: norms from global (L2-hot)
  float invy[4];
#pragma unroll
  for (int ct = 0; ct < 4; ++ct)
    invy[ct] = invny[(size_t)b * Mq + mt * TILE + wx * 64 + ct * 16 + ln15];

  // C/D layout per 16x16 tile: col = lane&15, row = (lane>>4)*4 + reg
#pragma unroll
  for (int rt = 0; rt < 4; ++rt) {
#pragma unroll
    for (int reg = 0; reg < 4; ++reg) {
      float bq = -1e30f;
      int bc = 0x7FFFFFFF;
#pragma unroll
      for (int ct = 0; ct < 4; ++ct) {
        float q = acc[rt][ct][reg] * invy[ct];
        int cg = mt * TILE + wx * 64 + ct * 16 + ln15;
        if (q > bq || (q == bq && cg < bc)) { bq = q; bc = cg; }
      }
#pragma unroll
      for (int m = 1; m <= 8; m <<= 1) {
        float q2 = __shfl_xor(bq, m);
        int c2 = __shfl_xor(bc, m);
        if (q2 > bq || (q2 == bq && c2 < bc)) { bq = q2; bc = c2; }
      }
      if (ln15 == 0) {
        int rloc = wy * 64 + rt * 16 + lq * 4 + reg;
        float conf = bq * invnx[(size_t)b * Nq + nt * TILE + rloc];
        // signed-max key: (sortable^0x80000000)<<32 | ~idx. Monotone in conf,
        // tie -> smallest idx. 0xAA..AA poison is a more-negative i64 than any
        // real key, so NO memset pass is needed.
        unsigned long long p =
            ((unsigned long long)(f2sortable(conf) ^ 0x80000000u) << 32) |
            (uint32_t)(~(uint32_t)bc);
        atomicMax((long long*)&best[(size_t)b * Nq + nt * TILE + rloc],
                  (long long)p);
      }
    }
  }
}

// ---------------------------------------------------------------------------
// FALLBACK PATH (verbatim 90 us kernel) -- used if ws_size can't hold the
// 32.3 MiB preprocessed operands.
// ---------------------------------------------------------------------------
__global__ __launch_bounds__(256, 3)
void simmax_kernel(const float* __restrict__ src, const float* __restrict__ dst,
                   unsigned long long* __restrict__ best) {
  __shared__ _Float16 Ah[TILE][LDS_S], Al[TILE][LDS_S];
  __shared__ _Float16 Bh[TILE][LDS_S], Bl[TILE][LDS_S];
  __shared__ float invnx_s[TILE], invny_s[TILE];

  const int b = blockIdx.z, nt = blockIdx.y, mt = blockIdx.x;
  const int tid = threadIdx.x;
  const int lane = tid & 63;
  const int wave = tid >> 6;
  const int wy = wave >> 1, wx = wave & 1;
  const int ln15 = lane & 15, lq = lane >> 4;

  const int sr = tid >> 1;
  const int sk = (tid & 1) * 16;
  const float* Ag = src + ((size_t)(b * Nq + nt * TILE + sr)) * Dq + sk;
  const float* Bg = dst + ((size_t)(b * Mq + mt * TILE + sr)) * Dq + sk;

  f32x4 acc[4][4];
#pragma unroll
  for (int i = 0; i < 4; ++i)
#pragma unroll
    for (int j = 0; j < 4; ++j) acc[i][j] = (f32x4){0.f, 0.f, 0.f, 0.f};
  float sqa = 0.f, sqb = 0.f;

  float av[16], bv[16];
  load16(av, Ag);
  load16(bv, Bg);

  for (int c = 0; c < NCH; ++c) {
    f16x8 ah2[2], al2[2], bh2[2], bl2[2];
    split8(&av[0], &ah2[0], &al2[0], sqa);
    split8(&av[8], &ah2[1], &al2[1], sqa);
    split8(&bv[0], &bh2[0], &bl2[0], sqb);
    split8(&bv[8], &bh2[1], &bl2[1], sqb);
    __syncthreads();
    *(f16x8*)&Ah[sr][sk]     = ah2[0];
    *(f16x8*)&Ah[sr][sk + 8] = ah2[1];
    *(f16x8*)&Al[sr][sk]     = al2[0];
    *(f16x8*)&Al[sr][sk + 8] = al2[1];
    *(f16x8*)&Bh[sr][sk]     = bh2[0];
    *(f16x8*)&Bh[sr][sk + 8] = bh2[1];
    *(f16x8*)&Bl[sr][sk]     = bl2[0];
    *(f16x8*)&Bl[sr][sk + 8] = bl2[1];
    __syncthreads();

    if (c + 1 < NCH) {
      load16(av, Ag + (c + 1) * KC);
      load16(bv, Bg + (c + 1) * KC);
    }

    f16x8 bhf[4], blf[4];
#pragma unroll
    for (int ct = 0; ct < 4; ++ct) {
      int rowb = wx * 64 + ct * 16 + ln15;
      bhf[ct] = *(const f16x8*)&Bh[rowb][lq * 8];
      blf[ct] = *(const f16x8*)&Bl[rowb][lq * 8];
    }
#pragma unroll
    for (int rt = 0; rt < 4; ++rt) {
      int rowa = wy * 64 + rt * 16 + ln15;
      f16x8 ahf = *(const f16x8*)&Ah[rowa][lq * 8];
      f16x8 alf = *(const f16x8*)&Al[rowa][lq * 8];
#pragma unroll
      for (int ct = 0; ct < 4; ++ct) {
        acc[rt][ct] = __builtin_amdgcn_mfma_f32_16x16x32_f16(ahf, bhf[ct], acc[rt][ct], 0, 0, 0);
        acc[rt][ct] = __builtin_amdgcn_mfma_f32_16x16x32_f16(ahf, blf[ct], acc[rt][ct], 0, 0, 0);
        acc[rt][ct] = __builtin_amdgcn_mfma_f32_16x16x32_f16(alf, bhf[ct], acc[rt][ct], 0, 0, 0);
      }
    }
  }

  sqa += __shfl_xor(sqa, 1);
  sqb += __shfl_xor(sqb, 1);
  if ((tid & 1) == 0) {
    invnx_s[sr] = 1.0f / sqrtf(sqa);
    invny_s[sr] = 1.0f / sqrtf(sqb);
  }
  __syncthreads();

  float invny[4];
#pragma unroll
  for (int ct = 0; ct < 4; ++ct) invny[ct] = invny_s[wx * 64 + ct * 16 + ln15];

#pragma unroll
  for (int rt = 0; rt < 4; ++rt) {
#pragma unroll
    for (int reg = 0; reg < 4; ++reg) {
      float bq = -1e30f;
      int bc = 0x7FFFFFFF;
#pragma unroll
      for (int ct = 0; ct < 4; ++ct) {
        float q = acc[rt][ct][reg] * invny[ct];
        int cg = mt * TILE + wx * 64 + ct * 16 + ln15;
        if (q > bq || (q == bq && cg < bc)) { bq = q; bc = cg; }
      }
#pragma unroll
      for (int m = 1; m <= 8; m <<= 1) {
        float q2 = __shfl_xor(bq, m);
        int c2 = __shfl_xor(bc, m);
        if (q2 > bq || (q2 == bq && c2 < bc)) { bq = q2; bc = c2; }
      }
      if (ln15 == 0) {
        int rloc = wy * 64 + rt * 16 + lq * 4 + reg;
        float conf = bq * invnx_s[rloc];
        unsigned long long p =
            ((unsigned long long)(f2sortable(conf) ^ 0x80000000u) << 32) |
            (uint32_t)(~(uint32_t)bc);
        atomicMax((long long*)&best[(size_t)b * Nq + nt * TILE + rloc],
                  (long long)p);
      }
    }
  }
}

__global__ void finalize_kernel(const unsigned long long* __restrict__ best,
                                const float* __restrict__ pts,
                                float* __restrict__ out) {
  int i = blockIdx.x * blockDim.x + threadIdx.x;
  if (i >= Bq * Nq) return;
  unsigned long long p = best[i];
  uint32_t s = (uint32_t)(p >> 32) ^ 0x80000000u;
  int idx = (int)(~(uint32_t)(p & 0xFFFFFFFFull));
  float conf = sortable2f(s);
  int b = i / Nq;
  const float* q = pts + ((size_t)b * Mq + (size_t)idx) * 2;
  out[(size_t)i * 2 + 0] = q[0];
  out[(size_t)i * 2 + 1] = q[1];
  out[(size_t)(Bq * Nq) * 2 + i] = conf;  // confidence block after matched pts
}

extern "C" void kernel_launch(void* const* d_in, const int* in_sizes, int n_in,
                              void* d_out, int out_size, void* d_ws, size_t ws_size,
                              hipStream_t stream) {
  const float* src = (const float*)d_in[0];
  const float* dst = (const float*)d_in[1];
  const float* pts = (const float*)d_in[2];
  float* out = (float*)d_out;

  unsigned long long* best = (unsigned long long*)d_ws;  // 16384 * 8 B

  constexpr size_t BEST_B = (size_t)Bq * Nq * 8;           // 128 KiB
  constexpr size_t HL_B   = (size_t)Bq * 2048 * Dq * 2;    // 8 MiB per array
  constexpr size_t INV_B  = (size_t)Bq * 2048 * 4;         // 64 KiB
  constexpr size_t NEED   = BEST_B + 4 * HL_B + 2 * INV_B; // ~32.3 MiB

  if (ws_size >= NEED) {
    uint8_t* w = (uint8_t*)d_ws + BEST_B;
    _Float16* Ah = (_Float16*)(w);
    _Float16* Al = (_Float16*)(w + 1 * HL_B);
    _Float16* Bh = (_Float16*)(w + 2 * HL_B);
    _Float16* Bl = (_Float16*)(w + 3 * HL_B);
    float* invnx = (float*)(w + 4 * HL_B);
    float* invny = (float*)(w + 4 * HL_B + INV_B);

    prep_kernel<<<dim3(4096, 2, 1), 256, 0, stream>>>(src, dst, Ah, Al, Bh, Bl,
                                                      invnx, invny);
    simmax_reg<<<dim3(2048, 1, 1), 256, 0, stream>>>(Ah, Al, Bh, Bl,
                                                     invnx, invny, best);
  } else {
    simmax_kernel<<<dim3(Mq / TILE, Nq / TILE, Bq), 256, 0, stream>>>(src, dst,
                                                                      best);
  }
  {
    int blocks = (Bq * Nq + 255) / 256;
    finalize_kernel<<<blocks, 256, 0, stream>>>(best, pts, out);
  }
}

// Round 4
// 164.246 us; speedup vs baseline: 1.1052x; 1.1052x over previous
//
#include <hip/hip_runtime.h>
#include <stdint.h>

constexpr int Bq = 8, Nq = 2048, Mq = 2048, Dq = 256;
constexpr int TILE = 128;          // 128x128 output tile per block
constexpr int KC = 32;             // fp32 k per chunk == MFMA K
constexpr int NCH = Dq / KC;       // 8 chunks
constexpr int LDS_S = 40;          // fallback kernel: 80B row stride

typedef float f32x4 __attribute__((ext_vector_type(4)));
typedef _Float16 f16x8 __attribute__((ext_vector_type(8)));
typedef _Float16 f16x4 __attribute__((ext_vector_type(4)));
typedef __fp16 fp16x2 __attribute__((ext_vector_type(2)));  // cvt_pkrtz native type

__device__ __forceinline__ uint32_t f2sortable(float f) {
  uint32_t u = __float_as_uint(f);
  return (u & 0x80000000u) ? ~u : (u | 0x80000000u);
}
__device__ __forceinline__ float sortable2f(uint32_t s) {
  uint32_t u = (s & 0x80000000u) ? (s ^ 0x80000000u) : ~s;
  return __uint_as_float(u);
}

__device__ __forceinline__ void load16(float* d, const float* __restrict__ p) {
  *(float4*)&d[0]  = *(const float4*)(p + 0);
  *(float4*)&d[4]  = *(const float4*)(p + 4);
  *(float4*)&d[8]  = *(const float4*)(p + 8);
  *(float4*)&d[12] = *(const float4*)(p + 12);
}

// Truncation split: h = x with low 13 mantissa bits cleared (exactly f16-
// representable; residual x-h exact by Sterbenz). al kept UNSCALED so all
// three MFMA terms share one accumulator: a.b ~= ah.bh + ah.bl + al.bh.
// Dropped al.bl ~ 2^-21|a||b| -> sim error ~1e-8; f16-denorm loss on tiny
// al -> sim error < 5e-7. Both negligible vs mean argmax gap 0.013.
__device__ __forceinline__ void split8(const float* x, f16x8* hi, f16x8* lo,
                                       float& sq) {
  union { f16x8 v; fp16x2 p[4]; } H, L;
#pragma unroll
  for (int j = 0; j < 4; ++j) {
    float x0 = x[2 * j], x1 = x[2 * j + 1];
    sq = fmaf(x0, x0, sq);
    sq = fmaf(x1, x1, sq);
    float h0 = __uint_as_float(__float_as_uint(x0) & 0xFFFFE000u);
    float h1 = __uint_as_float(__float_as_uint(x1) & 0xFFFFE000u);
    H.p[j] = __builtin_amdgcn_cvt_pkrtz(h0, h1);          // exact (13-bit mantissa)
    L.p[j] = __builtin_amdgcn_cvt_pkrtz(x0 - h0, x1 - h1); // RTZ on residual: fine
  }
  *hi = H.v;
  *lo = L.v;
}

// ---------------------------------------------------------------------------
// Preprocess fp32 -> chunked f16 hi/lo + inv-norms. Layout X[b][chunk][row][32]
// f16 (64 B rows): a (tile,chunk) slab of 128 rows is 8 KB CONTIGUOUS ->
// global_load_lds width-16 with linear LDS destination.
// ---------------------------------------------------------------------------

__global__ __launch_bounds__(256)
void prep_kernel(const float* __restrict__ src, const float* __restrict__ dst,
                 _Float16* __restrict__ Ah, _Float16* __restrict__ Al,
                 _Float16* __restrict__ Bh, _Float16* __restrict__ Bl,
                 float* __restrict__ invnx, float* __restrict__ invny) {
  const int lane = threadIdx.x & 63;
  const int wv = threadIdx.x >> 6;
  const int r = blockIdx.x * 4 + wv;  // global row 0..16383 (one wave per row)

  const float* x;
  _Float16 *h, *l;
  float* inv;
  if (blockIdx.y == 0) { x = src; h = Ah; l = Al; inv = invnx; }
  else                 { x = dst; h = Bh; l = Bl; inv = invny; }

  // lane covers 4 consecutive k: coalesced 1 KB/wave read
  float4 v = *(const float4*)(x + (size_t)r * Dq + lane * 4);
  float sq = 0.f;
  union { f16x4 v; fp16x2 p[2]; } H, L;
  float e[4] = {v.x, v.y, v.z, v.w};
#pragma unroll
  for (int j = 0; j < 2; ++j) {
    float x0 = e[2 * j], x1 = e[2 * j + 1];
    sq = fmaf(x0, x0, sq);
    sq = fmaf(x1, x1, sq);
    float h0 = __uint_as_float(__float_as_uint(x0) & 0xFFFFE000u);
    float h1 = __uint_as_float(__float_as_uint(x1) & 0xFFFFE000u);
    H.p[j] = __builtin_amdgcn_cvt_pkrtz(h0, h1);
    L.p[j] = __builtin_amdgcn_cvt_pkrtz(x0 - h0, x1 - h1);
  }
#pragma unroll
  for (int m = 1; m <= 32; m <<= 1) sq += __shfl_xor(sq, m);

  const int b = r >> 11, row = r & 2047;
  const int c = lane >> 3, ko = (lane & 7) * 4;  // chunk, k-within-chunk
  size_t idx = ((size_t)(b * NCH + c) * 2048 + row) * KC + ko;
  *(f16x4*)&h[idx] = H.v;
  *(f16x4*)&l[idx] = L.v;
  if (lane == 0) inv[r] = 1.0f / sqrtf(sq);  // norms ~16; eps clamp never active
}

// one wave stages one 8 KB array-slab: 8 x global_load_lds_dwordx4
// (LDS dest is wave-uniform base + lane*16 by HW; global src is per-lane)
__device__ __forceinline__ void stage(const _Float16* g, _Float16* l, int lane) {
  const char* gc = (const char*)g + lane * 16;
  char* lc = (char*)l;
#pragma unroll
  for (int i = 0; i < 8; ++i)
    __builtin_amdgcn_global_load_lds(
        (const __attribute__((address_space(1))) void*)(gc + i * 1024),
        (__attribute__((address_space(3))) void*)(lc + i * 1024),
        16, 0, 0);
}

// ---------------------------------------------------------------------------
// Main kernel: T3 2-phase minimum (stage-early, ONE barrier per chunk — the
// m97 structure) COMBINED with the T1 XCD swizzle. Round 1 ran this structure
// without the swizzle: staging loads were ~900-cyc HBM misses (FETCH 74 MB),
// marginally uncovered by the 931-cyc MFMA phase -> barrier convoy. Round 2
// proved the swizzle makes staging L2-hot (FETCH 16.6 MB, ~250 cyc), which
// the MFMA phase covers ~4x over. The vmcnt(0) drain at __syncthreads is
// then nearly free: each wave's 8 stage loads were issued a full MFMA-phase
// earlier and have long returned.
// ---------------------------------------------------------------------------

__global__ __launch_bounds__(256, 2)
void simmax_mfma(const _Float16* __restrict__ Ah, const _Float16* __restrict__ Al,
                 const _Float16* __restrict__ Bh, const _Float16* __restrict__ Bl,
                 const float* __restrict__ invnx, const float* __restrict__ invny,
                 unsigned long long* __restrict__ best) {
  // double-buffered: [buf][array Ah,Al,Bh,Bl][row][k] = 64 KiB -> 2 blocks/CU
  __shared__ __align__(16) _Float16 lds[2][4][TILE][KC];

  // T1 XCD swizzle (bijective: 2048 % 8 == 0). XCD k owns the 256 tiles of
  // b=k: per-XCD working set = A(b)+B(b) = 4 MB = one L2. Validated round 2:
  // FETCH_SIZE 74 -> 16.6 MB. Within an XCD, mt varies fastest so A slabs
  // are re-hit back-to-back.
  const int orig = blockIdx.x;
  const int logical = (orig & 7) * 256 + (orig >> 3);
  const int b = logical >> 8;
  const int nt = (logical >> 4) & 15;
  const int mt = logical & 15;

  const int tid = threadIdx.x;
  const int lane = tid & 63;
  const int wave = tid >> 6;
  const int wy = wave >> 1, wx = wave & 1;  // wave tile: rows wy*64, cols wx*64
  const int ln15 = lane & 15, lq = lane >> 4;

  // wave w stages array w (A-arrays keyed by nt, B-arrays by mt)
  const _Float16* garr = (wave == 0) ? Ah : (wave == 1) ? Al
                        : (wave == 2) ? Bh : Bl;
  const int grow = ((wave < 2) ? nt : mt) * TILE;
  const _Float16* g0 = garr + ((size_t)(b * NCH) * 2048 + grow) * KC;
  constexpr size_t CSTR = (size_t)2048 * KC;  // chunk stride in elements

  f32x4 acc[4][4];
#pragma unroll
  for (int i = 0; i < 4; ++i)
#pragma unroll
    for (int j = 0; j < 4; ++j) acc[i][j] = (f32x4){0.f, 0.f, 0.f, 0.f};

  stage(g0, &lds[0][wave][0][0], lane);
  __syncthreads();  // drains vmcnt: buf0 ready

#pragma unroll
  for (int c = 0; c < NCH; ++c) {
    const int cb = c & 1;
    // issue next-chunk prefetch FIRST; its vmcnt drain happens at the
    // end-of-iter barrier, fully covered by ~930 cyc of MFMAs below.
    if (c + 1 < NCH)
      stage(g0 + (size_t)(c + 1) * CSTR, &lds[cb ^ 1][wave][0][0], lane);

    // A/B operand layout: [row = lane&15][k = (lane>>4)*8 + j]
    f16x8 bhf[4], blf[4];
#pragma unroll
    for (int ct = 0; ct < 4; ++ct) {
      const int rb = wx * 64 + ct * 16 + ln15;
      bhf[ct] = *(const f16x8*)&lds[cb][2][rb][lq * 8];
      blf[ct] = *(const f16x8*)&lds[cb][3][rb][lq * 8];
    }
#pragma unroll
    for (int rt = 0; rt < 4; ++rt) {
      const int ra = wy * 64 + rt * 16 + ln15;
      f16x8 ahf = *(const f16x8*)&lds[cb][0][ra][lq * 8];
      f16x8 alf = *(const f16x8*)&lds[cb][1][ra][lq * 8];
#pragma unroll
      for (int ct = 0; ct < 4; ++ct) {
        acc[rt][ct] = __builtin_amdgcn_mfma_f32_16x16x32_f16(ahf, bhf[ct], acc[rt][ct], 0, 0, 0);
        acc[rt][ct] = __builtin_amdgcn_mfma_f32_16x16x32_f16(ahf, blf[ct], acc[rt][ct], 0, 0, 0);
        acc[rt][ct] = __builtin_amdgcn_mfma_f32_16x16x32_f16(alf, bhf[ct], acc[rt][ct], 0, 0, 0);
      }
    }
    if (c + 1 < NCH) __syncthreads();  // publish staged buf, guard overwrite
  }

  // epilogue: norms from global (L2-hot), no LDS round-trip
  float invy[4];
#pragma unroll
  for (int ct = 0; ct < 4; ++ct)
    invy[ct] = invny[(size_t)b * Mq + mt * TILE + wx * 64 + ct * 16 + ln15];

  // C/D layout per 16x16 tile: col = lane&15, row = (lane>>4)*4 + reg
#pragma unroll
  for (int rt = 0; rt < 4; ++rt) {
#pragma unroll
    for (int reg = 0; reg < 4; ++reg) {
      float bq = -1e30f;
      int bc = 0x7FFFFFFF;
#pragma unroll
      for (int ct = 0; ct < 4; ++ct) {
        float q = acc[rt][ct][reg] * invy[ct];
        int cg = mt * TILE + wx * 64 + ct * 16 + ln15;
        if (q > bq || (q == bq && cg < bc)) { bq = q; bc = cg; }
      }
#pragma unroll
      for (int m = 1; m <= 8; m <<= 1) {
        float q2 = __shfl_xor(bq, m);
        int c2 = __shfl_xor(bc, m);
        if (q2 > bq || (q2 == bq && c2 < bc)) { bq = q2; bc = c2; }
      }
      if (ln15 == 0) {
        int rloc = wy * 64 + rt * 16 + lq * 4 + reg;
        float conf = bq * invnx[(size_t)b * Nq + nt * TILE + rloc];
        // signed-max key: (sortable^0x80000000)<<32 | ~idx. Monotone in conf,
        // tie -> smallest idx. 0xAA..AA poison is a more-negative i64 than any
        // real key, so NO memset pass is needed.
        unsigned long long p =
            ((unsigned long long)(f2sortable(conf) ^ 0x80000000u) << 32) |
            (uint32_t)(~(uint32_t)bc);
        atomicMax((long long*)&best[(size_t)b * Nq + nt * TILE + rloc],
                  (long long)p);
      }
    }
  }
}

// ---------------------------------------------------------------------------
// FALLBACK PATH (verbatim 90 us kernel) -- used if ws_size can't hold the
// 32.3 MiB preprocessed operands.
// ---------------------------------------------------------------------------
__global__ __launch_bounds__(256, 3)
void simmax_kernel(const float* __restrict__ src, const float* __restrict__ dst,
                   unsigned long long* __restrict__ best) {
  __shared__ _Float16 Ah[TILE][LDS_S], Al[TILE][LDS_S];
  __shared__ _Float16 Bh[TILE][LDS_S], Bl[TILE][LDS_S];
  __shared__ float invnx_s[TILE], invny_s[TILE];

  const int b = blockIdx.z, nt = blockIdx.y, mt = blockIdx.x;
  const int tid = threadIdx.x;
  const int lane = tid & 63;
  const int wave = tid >> 6;
  const int wy = wave >> 1, wx = wave & 1;
  const int ln15 = lane & 15, lq = lane >> 4;

  const int sr = tid >> 1;
  const int sk = (tid & 1) * 16;
  const float* Ag = src + ((size_t)(b * Nq + nt * TILE + sr)) * Dq + sk;
  const float* Bg = dst + ((size_t)(b * Mq + mt * TILE + sr)) * Dq + sk;

  f32x4 acc[4][4];
#pragma unroll
  for (int i = 0; i < 4; ++i)
#pragma unroll
    for (int j = 0; j < 4; ++j) acc[i][j] = (f32x4){0.f, 0.f, 0.f, 0.f};
  float sqa = 0.f, sqb = 0.f;

  float av[16], bv[16];
  load16(av, Ag);
  load16(bv, Bg);

  for (int c = 0; c < NCH; ++c) {
    f16x8 ah2[2], al2[2], bh2[2], bl2[2];
    split8(&av[0], &ah2[0], &al2[0], sqa);
    split8(&av[8], &ah2[1], &al2[1], sqa);
    split8(&bv[0], &bh2[0], &bl2[0], sqb);
    split8(&bv[8], &bh2[1], &bl2[1], sqb);
    __syncthreads();
    *(f16x8*)&Ah[sr][sk]     = ah2[0];
    *(f16x8*)&Ah[sr][sk + 8] = ah2[1];
    *(f16x8*)&Al[sr][sk]     = al2[0];
    *(f16x8*)&Al[sr][sk + 8] = al2[1];
    *(f16x8*)&Bh[sr][sk]     = bh2[0];
    *(f16x8*)&Bh[sr][sk + 8] = bh2[1];
    *(f16x8*)&Bl[sr][sk]     = bl2[0];
    *(f16x8*)&Bl[sr][sk + 8] = bl2[1];
    __syncthreads();

    if (c + 1 < NCH) {
      load16(av, Ag + (c + 1) * KC);
      load16(bv, Bg + (c + 1) * KC);
    }

    f16x8 bhf[4], blf[4];
#pragma unroll
    for (int ct = 0; ct < 4; ++ct) {
      int rowb = wx * 64 + ct * 16 + ln15;
      bhf[ct] = *(const f16x8*)&Bh[rowb][lq * 8];
      blf[ct] = *(const f16x8*)&Bl[rowb][lq * 8];
    }
#pragma unroll
    for (int rt = 0; rt < 4; ++rt) {
      int rowa = wy * 64 + rt * 16 + ln15;
      f16x8 ahf = *(const f16x8*)&Ah[rowa][lq * 8];
      f16x8 alf = *(const f16x8*)&Al[rowa][lq * 8];
#pragma unroll
      for (int ct = 0; ct < 4; ++ct) {
        acc[rt][ct] = __builtin_amdgcn_mfma_f32_16x16x32_f16(ahf, bhf[ct], acc[rt][ct], 0, 0, 0);
        acc[rt][ct] = __builtin_amdgcn_mfma_f32_16x16x32_f16(ahf, blf[ct], acc[rt][ct], 0, 0, 0);
        acc[rt][ct] = __builtin_amdgcn_mfma_f32_16x16x32_f16(alf, bhf[ct], acc[rt][ct], 0, 0, 0);
      }
    }
  }

  sqa += __shfl_xor(sqa, 1);
  sqb += __shfl_xor(sqb, 1);
  if ((tid & 1) == 0) {
    invnx_s[sr] = 1.0f / sqrtf(sqa);
    invny_s[sr] = 1.0f / sqrtf(sqb);
  }
  __syncthreads();

  float invny[4];
#pragma unroll
  for (int ct = 0; ct < 4; ++ct) invny[ct] = invny_s[wx * 64 + ct * 16 + ln15];

#pragma unroll
  for (int rt = 0; rt < 4; ++rt) {
#pragma unroll
    for (int reg = 0; reg < 4; ++reg) {
      float bq = -1e30f;
      int bc = 0x7FFFFFFF;
#pragma unroll
      for (int ct = 0; ct < 4; ++ct) {
        float q = acc[rt][ct][reg] * invny[ct];
        int cg = mt * TILE + wx * 64 + ct * 16 + ln15;
        if (q > bq || (q == bq && cg < bc)) { bq = q; bc = cg; }
      }
#pragma unroll
      for (int m = 1; m <= 8; m <<= 1) {
        float q2 = __shfl_xor(bq, m);
        int c2 = __shfl_xor(bc, m);
        if (q2 > bq || (q2 == bq && c2 < bc)) { bq = q2; bc = c2; }
      }
      if (ln15 == 0) {
        int rloc = wy * 64 + rt * 16 + lq * 4 + reg;
        float conf = bq * invnx_s[rloc];
        unsigned long long p =
            ((unsigned long long)(f2sortable(conf) ^ 0x80000000u) << 32) |
            (uint32_t)(~(uint32_t)bc);
        atomicMax((long long*)&best[(size_t)b * Nq + nt * TILE + rloc],
                  (long long)p);
      }
    }
  }
}

__global__ void finalize_kernel(const unsigned long long* __restrict__ best,
                                const float* __restrict__ pts,
                                float* __restrict__ out) {
  int i = blockIdx.x * blockDim.x + threadIdx.x;
  if (i >= Bq * Nq) return;
  unsigned long long p = best[i];
  uint32_t s = (uint32_t)(p >> 32) ^ 0x80000000u;
  int idx = (int)(~(uint32_t)(p & 0xFFFFFFFFull));
  float conf = sortable2f(s);
  int b = i / Nq;
  const float* q = pts + ((size_t)b * Mq + (size_t)idx) * 2;
  out[(size_t)i * 2 + 0] = q[0];
  out[(size_t)i * 2 + 1] = q[1];
  out[(size_t)(Bq * Nq) * 2 + i] = conf;  // confidence block after matched pts
}

extern "C" void kernel_launch(void* const* d_in, const int* in_sizes, int n_in,
                              void* d_out, int out_size, void* d_ws, size_t ws_size,
                              hipStream_t stream) {
  const float* src = (const float*)d_in[0];
  const float* dst = (const float*)d_in[1];
  const float* pts = (const float*)d_in[2];
  float* out = (float*)d_out;

  unsigned long long* best = (unsigned long long*)d_ws;  // 16384 * 8 B

  constexpr size_t BEST_B = (size_t)Bq * Nq * 8;           // 128 KiB
  constexpr size_t HL_B   = (size_t)Bq * 2048 * Dq * 2;    // 8 MiB per array
  constexpr size_t INV_B  = (size_t)Bq * 2048 * 4;         // 64 KiB
  constexpr size_t NEED   = BEST_B + 4 * HL_B + 2 * INV_B; // ~32.3 MiB

  if (ws_size >= NEED) {
    uint8_t* w = (uint8_t*)d_ws + BEST_B;
    _Float16* Ah = (_Float16*)(w);
    _Float16* Al = (_Float16*)(w + 1 * HL_B);
    _Float16* Bh = (_Float16*)(w + 2 * HL_B);
    _Float16* Bl = (_Float16*)(w + 3 * HL_B);
    float* invnx = (float*)(w + 4 * HL_B);
    float* invny = (float*)(w + 4 * HL_B + INV_B);

    prep_kernel<<<dim3(4096, 2, 1), 256, 0, stream>>>(src, dst, Ah, Al, Bh, Bl,
                                                      invnx, invny);
    simmax_mfma<<<dim3(2048, 1, 1), 256, 0, stream>>>(Ah, Al, Bh, Bl,
                                                      invnx, invny, best);
  } else {
    simmax_kernel<<<dim3(Mq / TILE, Nq / TILE, Bq), 256, 0, stream>>>(src, dst,
                                                                      best);
  }
  {
    int blocks = (Bq * Nq + 255) / 256;
    finalize_kernel<<<blocks, 256, 0, stream>>>(best, pts, out);
  }
}